// Round 5
// baseline (288.223 us; speedup 1.0000x reference)
//
#include <hip/hip_runtime.h>

typedef __attribute__((ext_vector_type(4))) float f32x4;
typedef __attribute__((ext_vector_type(8))) short bf16x8;
typedef __attribute__((ext_vector_type(4))) unsigned short u16x4;

static __device__ __forceinline__ unsigned short f2bf(float f) {
    union { float f; unsigned int u; } a; a.f = f;
    unsigned int u = a.u;
    unsigned int r = (u + 0x7FFFu + ((u >> 16) & 1u)) >> 16;
    return (unsigned short)r;
}
static __device__ __forceinline__ float bf2f(unsigned short h) {
    union { unsigned int u; float f; } a; a.u = ((unsigned int)h) << 16;
    return a.f;
}
static __device__ __forceinline__ unsigned lds_off(const void* p) {
    return (unsigned)(unsigned long long)(const __attribute__((address_space(3))) void*)p;
}

// ---------------- convert x (fp32 -> bf16), vectorized ----------------
__global__ __launch_bounds__(256) void cvt_f32_bf16(const float* __restrict__ in,
                                                    unsigned short* __restrict__ out) {
    long long i = ((long long)blockIdx.x * 256 + threadIdx.x) * 4;
    float4 f = *(const float4*)(in + i);
    u16x4 u;
    u[0] = f2bf(f.x); u[1] = f2bf(f.y); u[2] = f2bf(f.z); u[3] = f2bf(f.w);
    *(u16x4*)(out + i) = u;
}

// ---------------- transpose W [1024][1024] f32 -> Wt [1024][1024] bf16 ----------------
__global__ __launch_bounds__(256) void transpose_w(const float* __restrict__ W0,
                                                   const float* __restrict__ W1,
                                                   const float* __restrict__ W2,
                                                   unsigned short* __restrict__ Wt) {
    __shared__ float t[32][33];
    int mat = blockIdx.z;
    const float* W = (mat == 0) ? W0 : (mat == 1) ? W1 : W2;
    unsigned short* out = Wt + (long long)mat * 1024 * 1024;
    int n0 = blockIdx.x * 32, k0 = blockIdx.y * 32;
    int tx = threadIdx.x, ty = threadIdx.y;   // 32 x 8
#pragma unroll
    for (int q = 0; q < 4; ++q)
        t[ty + 8 * q][tx] = W[(long long)(k0 + ty + 8 * q) * 1024 + n0 + tx];
    __syncthreads();
#pragma unroll
    for (int q = 0; q < 4; ++q)
        out[(long long)(n0 + ty + 8 * q) * 1024 + k0 + tx] = f2bf(t[tx][ty + 8 * q]);
}

// ====== 256x256 B^T GEMM, BK=32, 4-deep pipelined staging (3-tile prefetch lead) ======
// 512 threads, 8 waves (2M x 4N). LDS: A bufs [0,64K), B bufs [64K,128K), 16 KB/buf.
// One vmcnt(8)+barrier per K-32 tile; inline-asm ds_read_b128; XOR slot swizzle.
// OUT_MODE: 0 = bf16 out, 1 = f32 out.  BIAS_MODE: 0 none, 1 bias[n], 2 bias[m].
#define GBM 256
#define GBN 256

template<int OUT_MODE, int BIAS_MODE>
__global__ __launch_bounds__(512, 2) void gemm4b(
    const unsigned short* __restrict__ A, int lda, long long strideA,
    const unsigned short* __restrict__ B, int ldb, long long strideB,
    void* __restrict__ Cv, int ldc, long long strideC,
    const float* __restrict__ bias, int K, float scale)
{
    __shared__ __align__(16) char lds[131072];

    // ---- bijective XCD swizzle (all grids here have nwg % 8 == 0) ----
    const int gx = gridDim.x, gy = gridDim.y;
    int lin = blockIdx.x + gx * (blockIdx.y + gy * blockIdx.z);
    const int nwg = gx * gy * gridDim.z;
    const int qch = nwg >> 3;
    int swz = (lin & 7) * qch + (lin >> 3);
    const int bx = swz % gx; int t2 = swz / gx;
    const int by = t2 % gy;  const int bz = t2 / gy;

    const unsigned short* Ag = A + (long long)bz * strideA;
    const unsigned short* Bg = B + (long long)bz * strideB;
    const int m0 = by * GBM, n0 = bx * GBN;

    const int tid  = threadIdx.x;
    const int lane = tid & 63, w = tid >> 6;      // 8 waves
    const int wm = w >> 2, wn = w & 3;            // wave rows: wm*128, cols: wn*64
    const int l15 = lane & 15, l4 = lane >> 4;

    // staging: per tile, A = 2 calls x (8 waves x 16 rows), rows of 32 bf16 (64 B).
    // lane -> row lr = lane>>2, slot s = lane&3; source slot pre-swizzled s ^ (lr&3).
    const int lr  = lane >> 2;
    const int lsl = (lane & 3) ^ (lr & 3);
    const unsigned short* Asrc = Ag + (long long)(m0 + w * 16 + lr) * lda + lsl * 8;
    const unsigned short* Bsrc = Bg + (long long)(n0 + w * 16 + lr) * ldb + lsl * 8;

    f32x4 acc[8][4] = {};

    auto issueA = [&](int wb, int kt, int l) {
        __builtin_amdgcn_global_load_lds(
            (const __attribute__((address_space(1))) void*)(Asrc + (long long)(l * 128) * lda + kt),
            (__attribute__((address_space(3))) void*)(lds + wb + (l * 128 + w * 16) * 64), 16, 0, 0);
    };
    auto issueB = [&](int wb, int kt, int l) {
        __builtin_amdgcn_global_load_lds(
            (const __attribute__((address_space(1))) void*)(Bsrc + (long long)(l * 128) * ldb + kt),
            (__attribute__((address_space(3))) void*)(lds + 65536 + wb + (l * 128 + w * 16) * 64), 16, 0, 0);
    };

    // frag reads: row r holds logical slot q at LDS slot q ^ (r&3); q = l4, r&3 = l15&3.
    const unsigned ldsb  = lds_off(lds);
    const unsigned slotb = (unsigned)((l4 ^ (l15 & 3)) * 16);
    const unsigned aoffc = ldsb + (unsigned)((wm * 128 + l15) * 64) + slotb;
    const unsigned boffc = ldsb + 65536u + (unsigned)((wn * 64 + l15) * 64) + slotb;

    bf16x8 a0[4], a1[4], b0[4];
    auto readA = [&](bf16x8 (&af)[4], int rb, int mh) {
#pragma unroll
        for (int fi = 0; fi < 4; ++fi) {
            unsigned off = aoffc + rb + mh * 4096 + fi * 1024;
            asm volatile("ds_read_b128 %0, %1" : "=v"(af[fi]) : "v"(off));
        }
    };
    auto readB = [&](bf16x8 (&bf)[4], int rb) {
#pragma unroll
        for (int nj = 0; nj < 4; ++nj) {
            unsigned off = boffc + rb + nj * 1024;
            asm volatile("ds_read_b128 %0, %1" : "=v"(bf[nj]) : "v"(off));
        }
    };
    auto mfma16 = [&](int mh, bf16x8 (&af)[4], bf16x8 (&bf)[4]) {
#pragma unroll
        for (int fi = 0; fi < 4; ++fi)
#pragma unroll
            for (int nj = 0; nj < 4; ++nj)
                acc[mh * 4 + fi][nj] = __builtin_amdgcn_mfma_f32_16x16x32_bf16(
                    af[fi], bf[nj], acc[mh * 4 + fi][nj], 0, 0, 0);
    };

#define VMCNT8 asm volatile("s_waitcnt vmcnt(8)" ::: "memory")
#define VMCNT4 asm volatile("s_waitcnt vmcnt(4)" ::: "memory")
#define VMCNT0 asm volatile("s_waitcnt vmcnt(0)" ::: "memory")
#define LGKM0  asm volatile("s_waitcnt lgkmcnt(0)" ::: "memory")
#define SCHED0 __builtin_amdgcn_sched_barrier(0)
#define BARR   __builtin_amdgcn_s_barrier()
#define PRIO1  __builtin_amdgcn_s_setprio(1)
#define PRIO0  __builtin_amdgcn_s_setprio(0)

    const int NT = K >> 5;                // K-32 tiles
    // prologue: stage tiles 0,1,2 (4 loads each, FIFO order A0,A1,B0,B1)
#pragma unroll
    for (int t = 0; t < 3; ++t) {
        int wb = t * 16384, kt = t * 32;
        issueA(wb, kt, 0); issueA(wb, kt, 1);
        issueB(wb, kt, 0); issueB(wb, kt, 1);
    }

    int rb = 0;
    for (int t = 0; t < NT - 2; ++t) {
        VMCNT8; BARR; SCHED0;
        const int kt3 = (t + 3) * 32;
        const int wb = (rb + 49152) & 65535;
        const bool more = (t + 3) < NT;
        if (more) { issueA(wb, kt3, 0); issueA(wb, kt3, 1); }
        readB(b0, rb); readA(a0, rb, 0);
        LGKM0; SCHED0; PRIO1; mfma16(0, a0, b0); PRIO0;
        if (more) { issueB(wb, kt3, 0); issueB(wb, kt3, 1); }
        readA(a1, rb, 1);
        LGKM0; SCHED0; PRIO1; mfma16(1, a1, b0); PRIO0;
        rb = (rb + 16384) & 65535;
    }
    // tile NT-2: only NT-1's 4 loads may remain outstanding
    {
        VMCNT4; BARR; SCHED0;
        readB(b0, rb); readA(a0, rb, 0);
        LGKM0; SCHED0; PRIO1; mfma16(0, a0, b0); PRIO0;
        readA(a1, rb, 1);
        LGKM0; SCHED0; PRIO1; mfma16(1, a1, b0); PRIO0;
        rb = (rb + 16384) & 65535;
    }
    // tile NT-1: drain all
    {
        VMCNT0; BARR; SCHED0;
        readB(b0, rb); readA(a0, rb, 0);
        LGKM0; SCHED0; PRIO1; mfma16(0, a0, b0); PRIO0;
        readA(a1, rb, 1);
        LGKM0; SCHED0; PRIO1; mfma16(1, a1, b0); PRIO0;
    }

    // epilogue: C/D frag layout col = lane&15 (N), row = (lane>>4)*4 + r (M)
    const float* bias_v = bias;
    asm volatile("" : "+s"(bias_v));   // keep bias loads out of the counted region
    unsigned short* Cb = (unsigned short*)Cv;
    float* Cf = (float*)Cv;
    long long cbase = (long long)bz * strideC;
#pragma unroll
    for (int mh = 0; mh < 2; ++mh)
#pragma unroll
    for (int fi = 0; fi < 4; ++fi) {
#pragma unroll
        for (int nj = 0; nj < 4; ++nj) {
            int n = n0 + wn * 64 + nj * 16 + l15;
            float bn = (BIAS_MODE == 1) ? bias_v[n] : 0.0f;
#pragma unroll
            for (int r = 0; r < 4; ++r) {
                int m = m0 + wm * 128 + mh * 64 + fi * 16 + l4 * 4 + r;
                float v = acc[mh * 4 + fi][nj][r] * scale + bn;
                if (BIAS_MODE == 2) v += bias_v[m];
                long long idx = cbase + (long long)m * ldc + n;
                if (OUT_MODE == 0) Cb[idx] = f2bf(v);
                else               Cf[idx] = v;
            }
        }
    }
}

// ------- row softmax over bf16 scores, in place: S[row][2048] bf16 -> P bf16 -------
__global__ __launch_bounds__(256) void softmax_rows_bf16(unsigned short* __restrict__ S) {
    int row  = blockIdx.x * 4 + (threadIdx.x >> 6);
    int lane = threadIdx.x & 63;
    unsigned short* Srow = S + (long long)row * 2048;
    float v[32];
    float mx = -1e30f;
#pragma unroll
    for (int j = 0; j < 4; ++j) {
        bf16x8 h = *(const bf16x8*)(Srow + j * 512 + lane * 8);
#pragma unroll
        for (int e = 0; e < 8; ++e) {
            float f = bf2f((unsigned short)h[e]);
            v[j * 8 + e] = f;
            mx = fmaxf(mx, f);
        }
    }
#pragma unroll
    for (int o = 32; o; o >>= 1) mx = fmaxf(mx, __shfl_xor(mx, o));
    float sum = 0.0f;
#pragma unroll
    for (int e = 0; e < 32; ++e) {
        v[e] = __expf(v[e] - mx);
        sum += v[e];
    }
#pragma unroll
    for (int o = 32; o; o >>= 1) sum += __shfl_xor(sum, o);
    float inv = 1.0f / sum;
#pragma unroll
    for (int j = 0; j < 4; ++j) {
        bf16x8 h;
#pragma unroll
        for (int e = 0; e < 8; ++e) h[e] = (short)f2bf(v[j * 8 + e] * inv);
        *(bf16x8*)(Srow + j * 512 + lane * 8) = h;
    }
}

extern "C" void kernel_launch(void* const* d_in, const int* in_sizes, int n_in,
                              void* d_out, int out_size, void* d_ws, size_t ws_size,
                              hipStream_t stream) {
    (void)in_sizes; (void)n_in; (void)out_size; (void)ws_size;
    const float* x  = (const float*)d_in[0];
    const float* Wq = (const float*)d_in[1];
    const float* bq = (const float*)d_in[2];
    const float* Wk = (const float*)d_in[3];
    const float* bk = (const float*)d_in[4];
    const float* Wv = (const float*)d_in[5];
    const float* bv = (const float*)d_in[6];

    // workspace layout (bytes) — peak ~166 MiB
    char* ws = (char*)d_ws;
    unsigned short* Wt  = (unsigned short*)ws;                       //   6,291,456 B (q,k,v)
    unsigned short* Qb  = (unsigned short*)(ws + 6291456);           //  33,554,432
    unsigned short* Kb  = (unsigned short*)(ws + 39845888);          //  33,554,432
    unsigned short* Vt  = (unsigned short*)(ws + 73400320);          //  33,554,432
    unsigned short* xb  = (unsigned short*)(ws + 106954752);         //  33,554,432 (dead after V proj)
    unsigned short* Sb  = (unsigned short*)(ws + 106954752);         //  67,108,864 (bf16 scores, overlays xb)

    // 1) convert x -> bf16
    cvt_f32_bf16<<<dim3(16384), dim3(256), 0, stream>>>(x, xb);
    // 2) W^T -> bf16 (3 mats)
    transpose_w<<<dim3(32, 32, 3), dim3(32, 8), 0, stream>>>(Wq, Wk, Wv, Wt);

    // 3) Q = xb @ Wq + bq   -> bf16 [16384][1024]
    gemm4b<0, 1><<<dim3(4, 64, 1), dim3(512), 0, stream>>>(
        xb, 1024, 0, Wt, 1024, 0, Qb, 1024, 0, bq, 1024, 1.0f);
    // 4) K
    gemm4b<0, 1><<<dim3(4, 64, 1), dim3(512), 0, stream>>>(
        xb, 1024, 0, Wt + 1048576, 1024, 0, Kb, 1024, 0, bk, 1024, 1.0f);
    // 5) Vt[d][m] = sum_k Wvt[d][k] xb[m][k] + bv[d]  -> bf16 [1024][16384]
    gemm4b<0, 2><<<dim3(64, 4, 1), dim3(512), 0, stream>>>(
        Wt + 2097152, 1024, 0, xb, 1024, 0, Vt, 16384, 0, bv, 1024, 1.0f);

    // 6) scores: S[b][q][kv] = (Q @ K^T) * 1/32   -> bf16 (xb dead now)
    gemm4b<0, 0><<<dim3(8, 8, 8), dim3(512), 0, stream>>>(
        Qb, 1024, 2097152LL, Kb, 1024, 2097152LL,
        Sb, 2048, 4194304LL, nullptr, 1024, 0.03125f);

    // 7) softmax rows in place (bf16 -> bf16)
    softmax_rows_bf16<<<dim3(4096), dim3(256), 0, stream>>>(Sb);

    // 8) out[b][q][d] = P @ V = sum_kv P[q][kv] * Vt[d][b*2048+kv]
    gemm4b<1, 0><<<dim3(4, 8, 8), dim3(512), 0, stream>>>(
        Sb, 2048, 4194304LL,
        Vt, 16384, 2048LL,
        d_out, 1024, 2097152LL, nullptr, 2048, 1.0f);
}

// Round 6
// 285.783 us; speedup vs baseline: 1.0085x; 1.0085x over previous
//
#include <hip/hip_runtime.h>

typedef __attribute__((ext_vector_type(4))) float f32x4;
typedef __attribute__((ext_vector_type(8))) short bf16x8;
typedef __attribute__((ext_vector_type(4))) unsigned short u16x4;

static __device__ __forceinline__ unsigned short f2bf(float f) {
    union { float f; unsigned int u; } a; a.f = f;
    unsigned int u = a.u;
    unsigned int r = (u + 0x7FFFu + ((u >> 16) & 1u)) >> 16;
    return (unsigned short)r;
}
static __device__ __forceinline__ float bf2f(unsigned short h) {
    union { unsigned int u; float f; } a; a.u = ((unsigned int)h) << 16;
    return a.f;
}
static __device__ __forceinline__ unsigned lds_off(const void* p) {
    return (unsigned)(unsigned long long)(const __attribute__((address_space(3))) void*)p;
}

// ---------------- convert x (fp32 -> bf16), vectorized ----------------
__global__ __launch_bounds__(256) void cvt_f32_bf16(const float* __restrict__ in,
                                                    unsigned short* __restrict__ out) {
    long long i = ((long long)blockIdx.x * 256 + threadIdx.x) * 4;
    float4 f = *(const float4*)(in + i);
    u16x4 u;
    u[0] = f2bf(f.x); u[1] = f2bf(f.y); u[2] = f2bf(f.z); u[3] = f2bf(f.w);
    *(u16x4*)(out + i) = u;
}

// ---------------- transpose W [1024][1024] f32 -> Wt [1024][1024] bf16 ----------------
__global__ __launch_bounds__(256) void transpose_w(const float* __restrict__ W0,
                                                   const float* __restrict__ W1,
                                                   const float* __restrict__ W2,
                                                   unsigned short* __restrict__ Wt) {
    __shared__ float t[32][33];
    int mat = blockIdx.z;
    const float* W = (mat == 0) ? W0 : (mat == 1) ? W1 : W2;
    unsigned short* out = Wt + (long long)mat * 1024 * 1024;
    int n0 = blockIdx.x * 32, k0 = blockIdx.y * 32;
    int tx = threadIdx.x, ty = threadIdx.y;   // 32 x 8
#pragma unroll
    for (int q = 0; q < 4; ++q)
        t[ty + 8 * q][tx] = W[(long long)(k0 + ty + 8 * q) * 1024 + n0 + tx];
    __syncthreads();
#pragma unroll
    for (int q = 0; q < 4; ++q)
        out[(long long)(n0 + ty + 8 * q) * 1024 + k0 + tx] = f2bf(t[tx][ty + 8 * q]);
}

// ====== 256x256 B^T GEMM, BK=64, faithful 8-phase (m201-style) schedule ======
// 512 threads, 8 waves (2M x 4N). LDS: A bufs [0,64K), B bufs [64K,128K), 32 KB/buf.
// Per K-tile: 4 phases, each {ds_read frags; stage 1 half-tile; BARR; lgkm0; 16 MFMA; BARR};
// one vmcnt(2) per tile (phase 3). Stage slots: B0(t+1), A1(t+1), B1(t+1), A0(t+2).
// OUT_MODE: 0 = bf16 out, 1 = f32 out.  BIAS_MODE: 0 none, 1 bias[n], 2 bias[m].
#define GBM 256
#define GBN 256

template<int OUT_MODE, int BIAS_MODE>
__global__ __launch_bounds__(512, 2) void gemm8p(
    const unsigned short* __restrict__ A, int lda, long long strideA,
    const unsigned short* __restrict__ B, int ldb, long long strideB,
    void* __restrict__ Cv, int ldc, long long strideC,
    const float* __restrict__ bias, int K, float scale)
{
    __shared__ __align__(16) char lds[131072];

    // ---- bijective XCD swizzle (all grids here have nwg % 8 == 0) ----
    const int gx = gridDim.x, gy = gridDim.y;
    int lin = blockIdx.x + gx * (blockIdx.y + gy * blockIdx.z);
    const int nwg = gx * gy * gridDim.z;
    const int qch = nwg >> 3;
    int swz = (lin & 7) * qch + (lin >> 3);
    const int bx = swz % gx; int t2 = swz / gx;
    const int by = t2 % gy;  const int bz = t2 / gy;

    const unsigned short* Ag = A + (long long)bz * strideA;
    const unsigned short* Bg = B + (long long)bz * strideB;
    const int m0 = by * GBM, n0 = bx * GBN;

    const int tid  = threadIdx.x;
    const int lane = tid & 63, w = tid >> 6;      // 8 waves
    const int wm = w >> 2, wn = w & 3;            // wave rows: wm*128, cols: wn*64
    const int l15 = lane & 15, l4 = lane >> 4;

    // staging: rows of 128 B (64 bf16); per instr: 8 rows x 8 slots of 16 B per wave.
    // lane -> row lane>>3, slot lane&7; source slot pre-swizzled (lane&7)^(lane>>3).
    const int sr = lane >> 3;
    const int ss = (lane & 7) ^ sr;
    const unsigned short* Asrc = Ag + (long long)(m0 + w * 8 + sr) * lda + ss * 8;
    const unsigned short* Bsrc = Bg + (long long)(n0 + w * 8 + sr) * ldb + ss * 8;

    f32x4 acc[8][4] = {};

    // half h covers rows h*128..h*128+127 -> 2 instrs (i = 0,1), 64 rows each.
    auto stageA = [&](int p, int kt, int h) {
#pragma unroll
        for (int i = 0; i < 2; ++i)
            __builtin_amdgcn_global_load_lds(
                (const __attribute__((address_space(1))) void*)(Asrc + (long long)(h * 128 + i * 64) * lda + kt),
                (__attribute__((address_space(3))) void*)(lds + p * 32768 + (h * 128 + i * 64 + w * 8) * 128), 16, 0, 0);
    };
    auto stageB = [&](int p, int kt, int h) {
#pragma unroll
        for (int i = 0; i < 2; ++i)
            __builtin_amdgcn_global_load_lds(
                (const __attribute__((address_space(1))) void*)(Bsrc + (long long)(h * 128 + i * 64) * ldb + kt),
                (__attribute__((address_space(3))) void*)(lds + 65536 + p * 32768 + (h * 128 + i * 64 + w * 8) * 128), 16, 0, 0);
    };

    // read addressing: row r holds logical 16B slot q at LDS slot q ^ (r&7).
    const unsigned ldsb = lds_off(lds);
    const unsigned as0  = (unsigned)(((l4    ) ^ (l15 & 7)) * 16);
    const unsigned as1  = (unsigned)(((l4 + 4) ^ (l15 & 7)) * 16);
    const unsigned aRow = (unsigned)((wm * 128 + l15) * 128);
    const unsigned bRow = (unsigned)((wn * 64 + l15) * 128);

    bf16x8 a0[4], a1[4], b0[4], b1[4];
    auto readA = [&](bf16x8 (&af)[4], int p, int mh, int ks) {
        unsigned base = ldsb + (unsigned)(p * 32768) + aRow + (unsigned)(mh * 8192) + (ks ? as1 : as0);
#pragma unroll
        for (int fi = 0; fi < 4; ++fi) {
            unsigned off = base + (unsigned)(fi * 2048);
            asm volatile("ds_read_b128 %0, %1" : "=v"(af[fi]) : "v"(off));
        }
    };
    auto readB = [&](bf16x8 (&bf)[4], int p, int ks) {
        unsigned base = ldsb + 65536u + (unsigned)(p * 32768) + bRow + (ks ? as1 : as0);
#pragma unroll
        for (int nj = 0; nj < 4; ++nj) {
            unsigned off = base + (unsigned)(nj * 2048);
            asm volatile("ds_read_b128 %0, %1" : "=v"(bf[nj]) : "v"(off));
        }
    };
    auto mfma16 = [&](int mh, bf16x8 (&af)[4], bf16x8 (&bf)[4]) {
#pragma unroll
        for (int fi = 0; fi < 4; ++fi)
#pragma unroll
            for (int nj = 0; nj < 4; ++nj)
                acc[mh * 4 + fi][nj] = __builtin_amdgcn_mfma_f32_16x16x32_bf16(
                    af[fi], bf[nj], acc[mh * 4 + fi][nj], 0, 0, 0);
    };

#define VMCNT2 asm volatile("s_waitcnt vmcnt(2)" ::: "memory")
#define VMCNT0 asm volatile("s_waitcnt vmcnt(0)" ::: "memory")
#define LGKM0  asm volatile("s_waitcnt lgkmcnt(0)" ::: "memory")
#define SCHED0 __builtin_amdgcn_sched_barrier(0)
#define BARR   __builtin_amdgcn_s_barrier()
#define PRIO1  __builtin_amdgcn_s_setprio(1)
#define PRIO0  __builtin_amdgcn_s_setprio(0)

    const int NT = K >> 6;
    // prologue FIFO: tile0 {A0,A1,B0,B1} then A0(tile1)
    stageA(0, 0, 0); stageA(0, 0, 1); stageB(0, 0, 0); stageB(0, 0, 1);
    stageA(1, 64, 0);
    VMCNT2; BARR; SCHED0;        // tile 0's 8 loads done; A0(1) still in flight

    for (int t = 0; t < NT; ++t) {
        const int p = t & 1, q = p ^ 1;
        const int kt1 = (t + 1) << 6, kt2 = (t + 2) << 6;
        const bool s1 = (t + 1) < NT, s2 = (t + 2) < NT;
        // phase 0: (mh0, ks0)
        readA(a0, p, 0, 0); readB(b0, p, 0);
        if (s1) stageB(q, kt1, 0);
        BARR; LGKM0; SCHED0; PRIO1; mfma16(0, a0, b0); PRIO0; BARR;
        // phase 1: (mh1, ks0)
        readA(a1, p, 1, 0);
        if (s1) stageA(q, kt1, 1);
        BARR; LGKM0; SCHED0; PRIO1; mfma16(1, a1, b0); PRIO0; BARR;
        // phase 2: (mh0, ks1)
        readA(a0, p, 0, 1); readB(b1, p, 1);
        if (s1) stageB(q, kt1, 1);
        BARR; LGKM0; SCHED0; PRIO1; mfma16(0, a0, b1); PRIO0; BARR;
        // phase 3: (mh1, ks1)  — gate next tile's buffer
        readA(a1, p, 1, 1);
        if (s2) stageA(p, kt2, 0);
        if (t == NT - 1) { VMCNT0; } else { VMCNT2; }
        BARR; LGKM0; SCHED0; PRIO1; mfma16(1, a1, b1); PRIO0; BARR;
    }

    // epilogue: C/D frag layout col = lane&15 (N), row = (lane>>4)*4 + r (M)
    const float* bias_v = bias;
    asm volatile("" : "+s"(bias_v));   // keep bias loads out of the counted region
    unsigned short* Cb = (unsigned short*)Cv;
    float* Cf = (float*)Cv;
    long long cbase = (long long)bz * strideC;
#pragma unroll
    for (int mh = 0; mh < 2; ++mh)
#pragma unroll
    for (int fi = 0; fi < 4; ++fi) {
#pragma unroll
        for (int nj = 0; nj < 4; ++nj) {
            int n = n0 + wn * 64 + nj * 16 + l15;
            float bn = (BIAS_MODE == 1) ? bias_v[n] : 0.0f;
#pragma unroll
            for (int r = 0; r < 4; ++r) {
                int m = m0 + wm * 128 + mh * 64 + fi * 16 + l4 * 4 + r;
                float v = acc[mh * 4 + fi][nj][r] * scale + bn;
                if (BIAS_MODE == 2) v += bias_v[m];
                long long idx = cbase + (long long)m * ldc + n;
                if (OUT_MODE == 0) Cb[idx] = f2bf(v);
                else               Cf[idx] = v;
            }
        }
    }
}

// ------- row softmax over bf16 scores, in place: S[row][2048] bf16 -> P bf16 -------
__global__ __launch_bounds__(256) void softmax_rows_bf16(unsigned short* __restrict__ S) {
    int row  = blockIdx.x * 4 + (threadIdx.x >> 6);
    int lane = threadIdx.x & 63;
    unsigned short* Srow = S + (long long)row * 2048;
    float v[32];
    float mx = -1e30f;
#pragma unroll
    for (int j = 0; j < 4; ++j) {
        bf16x8 h = *(const bf16x8*)(Srow + j * 512 + lane * 8);
#pragma unroll
        for (int e = 0; e < 8; ++e) {
            float f = bf2f((unsigned short)h[e]);
            v[j * 8 + e] = f;
            mx = fmaxf(mx, f);
        }
    }
#pragma unroll
    for (int o = 32; o; o >>= 1) mx = fmaxf(mx, __shfl_xor(mx, o));
    float sum = 0.0f;
#pragma unroll
    for (int e = 0; e < 32; ++e) {
        v[e] = __expf(v[e] - mx);
        sum += v[e];
    }
#pragma unroll
    for (int o = 32; o; o >>= 1) sum += __shfl_xor(sum, o);
    float inv = 1.0f / sum;
#pragma unroll
    for (int j = 0; j < 4; ++j) {
        bf16x8 h;
#pragma unroll
        for (int e = 0; e < 8; ++e) h[e] = (short)f2bf(v[j * 8 + e] * inv);
        *(bf16x8*)(Srow + j * 512 + lane * 8) = h;
    }
}

extern "C" void kernel_launch(void* const* d_in, const int* in_sizes, int n_in,
                              void* d_out, int out_size, void* d_ws, size_t ws_size,
                              hipStream_t stream) {
    (void)in_sizes; (void)n_in; (void)out_size; (void)ws_size;
    const float* x  = (const float*)d_in[0];
    const float* Wq = (const float*)d_in[1];
    const float* bq = (const float*)d_in[2];
    const float* Wk = (const float*)d_in[3];
    const float* bk = (const float*)d_in[4];
    const float* Wv = (const float*)d_in[5];
    const float* bv = (const float*)d_in[6];

    // workspace layout (bytes) — peak ~166 MiB
    char* ws = (char*)d_ws;
    unsigned short* Wt  = (unsigned short*)ws;                       //   6,291,456 B (q,k,v)
    unsigned short* Qb  = (unsigned short*)(ws + 6291456);           //  33,554,432
    unsigned short* Kb  = (unsigned short*)(ws + 39845888);          //  33,554,432
    unsigned short* Vt  = (unsigned short*)(ws + 73400320);          //  33,554,432
    unsigned short* xb  = (unsigned short*)(ws + 106954752);         //  33,554,432 (dead after V proj)
    unsigned short* Sb  = (unsigned short*)(ws + 106954752);         //  67,108,864 (bf16 scores, overlays xb)

    // 1) convert x -> bf16
    cvt_f32_bf16<<<dim3(16384), dim3(256), 0, stream>>>(x, xb);
    // 2) W^T -> bf16 (3 mats)
    transpose_w<<<dim3(32, 32, 3), dim3(32, 8), 0, stream>>>(Wq, Wk, Wv, Wt);

    // 3) Q = xb @ Wq + bq   -> bf16 [16384][1024]
    gemm8p<0, 1><<<dim3(4, 64, 1), dim3(512), 0, stream>>>(
        xb, 1024, 0, Wt, 1024, 0, Qb, 1024, 0, bq, 1024, 1.0f);
    // 4) K
    gemm8p<0, 1><<<dim3(4, 64, 1), dim3(512), 0, stream>>>(
        xb, 1024, 0, Wt + 1048576, 1024, 0, Kb, 1024, 0, bk, 1024, 1.0f);
    // 5) Vt[d][m] = sum_k Wvt[d][k] xb[m][k] + bv[d]  -> bf16 [1024][16384]
    gemm8p<0, 2><<<dim3(64, 4, 1), dim3(512), 0, stream>>>(
        Wt + 2097152, 1024, 0, xb, 1024, 0, Vt, 16384, 0, bv, 1024, 1.0f);

    // 6) scores: S[b][q][kv] = (Q @ K^T) * 1/32   -> bf16 (xb dead now)
    gemm8p<0, 0><<<dim3(8, 8, 8), dim3(512), 0, stream>>>(
        Qb, 1024, 2097152LL, Kb, 1024, 2097152LL,
        Sb, 2048, 4194304LL, nullptr, 1024, 0.03125f);

    // 7) softmax rows in place (bf16 -> bf16)
    softmax_rows_bf16<<<dim3(4096), dim3(256), 0, stream>>>(Sb);

    // 8) out[b][q][d] = P @ V = sum_kv P[q][kv] * Vt[d][b*2048+kv]
    gemm8p<1, 0><<<dim3(4, 8, 8), dim3(512), 0, stream>>>(
        Sb, 2048, 4194304LL,
        Vt, 16384, 2048LL,
        d_out, 1024, 2097152LL, nullptr, 2048, 1.0f);
}

// Round 7
// 275.340 us; speedup vs baseline: 1.0468x; 1.0379x over previous
//
#include <hip/hip_runtime.h>

typedef __attribute__((ext_vector_type(4))) float f32x4;
typedef __attribute__((ext_vector_type(8))) short bf16x8;
typedef __attribute__((ext_vector_type(4))) unsigned short u16x4;

static __device__ __forceinline__ unsigned short f2bf(float f) {
    union { float f; unsigned int u; } a; a.f = f;
    unsigned int u = a.u;
    unsigned int r = (u + 0x7FFFu + ((u >> 16) & 1u)) >> 16;
    return (unsigned short)r;
}
static __device__ __forceinline__ float bf2f(unsigned short h) {
    union { unsigned int u; float f; } a; a.u = ((unsigned int)h) << 16;
    return a.f;
}
static __device__ __forceinline__ unsigned lds_off(const void* p) {
    return (unsigned)(unsigned long long)(const __attribute__((address_space(3))) void*)p;
}

// ---------------- convert x (fp32 -> bf16), vectorized ----------------
__global__ __launch_bounds__(256) void cvt_f32_bf16(const float* __restrict__ in,
                                                    unsigned short* __restrict__ out) {
    long long i = ((long long)blockIdx.x * 256 + threadIdx.x) * 4;
    float4 f = *(const float4*)(in + i);
    u16x4 u;
    u[0] = f2bf(f.x); u[1] = f2bf(f.y); u[2] = f2bf(f.z); u[3] = f2bf(f.w);
    *(u16x4*)(out + i) = u;
}

// ---------------- transpose W [1024][1024] f32 -> Wt [1024][1024] bf16 ----------------
__global__ __launch_bounds__(256) void transpose_w(const float* __restrict__ W0,
                                                   const float* __restrict__ W1,
                                                   const float* __restrict__ W2,
                                                   unsigned short* __restrict__ Wt) {
    __shared__ float t[32][33];
    int mat = blockIdx.z;
    const float* W = (mat == 0) ? W0 : (mat == 1) ? W1 : W2;
    unsigned short* out = Wt + (long long)mat * 1024 * 1024;
    int n0 = blockIdx.x * 32, k0 = blockIdx.y * 32;
    int tx = threadIdx.x, ty = threadIdx.y;   // 32 x 8
#pragma unroll
    for (int q = 0; q < 4; ++q)
        t[ty + 8 * q][tx] = W[(long long)(k0 + ty + 8 * q) * 1024 + n0 + tx];
    __syncthreads();
#pragma unroll
    for (int q = 0; q < 4; ++q)
        out[(long long)(n0 + ty + 8 * q) * 1024 + k0 + tx] = f2bf(t[tx][ty + 8 * q]);
}

// ====== 256x256 B^T GEMM, BK=64, phase-pipelined ds_read (counted lgkmcnt) ======
// 512 threads, 8 waves (2M x 4N). LDS: A bufs [0,64K), B bufs [64K,128K), 32 KB/buf.
// One vmcnt(0)+barrier gate per K-tile (staging has full-tile lead); each phase's
// fragment ds_reads are issued BEFORE the previous phase's MFMA cluster and waited
// with counted lgkmcnt so LDS streaming overlaps MFMA issue.
// OUT_MODE: 0 = bf16 out, 1 = f32 out.  BIAS_MODE: 0 none, 1 bias[n], 2 bias[m].
#define GBM 256
#define GBN 256

template<int OUT_MODE, int BIAS_MODE>
__global__ __launch_bounds__(512, 2) void gemmpp(
    const unsigned short* __restrict__ A, int lda, long long strideA,
    const unsigned short* __restrict__ B, int ldb, long long strideB,
    void* __restrict__ Cv, int ldc, long long strideC,
    const float* __restrict__ bias, int K, float scale)
{
    __shared__ __align__(16) char lds[131072];

    // ---- bijective XCD swizzle (all grids here have nwg % 8 == 0) ----
    const int gx = gridDim.x, gy = gridDim.y;
    int lin = blockIdx.x + gx * (blockIdx.y + gy * blockIdx.z);
    const int nwg = gx * gy * gridDim.z;
    const int qch = nwg >> 3;
    int swz = (lin & 7) * qch + (lin >> 3);
    const int bx = swz % gx; int t2 = swz / gx;
    const int by = t2 % gy;  const int bz = t2 / gy;

    const unsigned short* Ag = A + (long long)bz * strideA;
    const unsigned short* Bg = B + (long long)bz * strideB;
    const int m0 = by * GBM, n0 = bx * GBN;

    const int tid  = threadIdx.x;
    const int lane = tid & 63, w = tid >> 6;      // 8 waves
    const int wm = w >> 2, wn = w & 3;            // wave rows: wm*128, cols: wn*64
    const int l15 = lane & 15, l4 = lane >> 4;

    // staging: rows of 128 B (64 bf16); per instr: 8 rows x 8 slots of 16 B per wave.
    // lane -> row lane>>3, slot lane&7; source slot pre-swizzled (lane&7)^(lane>>3).
    const int sr = lane >> 3;
    const int ss = (lane & 7) ^ sr;
    const unsigned short* Asrc = Ag + (long long)(m0 + w * 8 + sr) * lda + ss * 8;
    const unsigned short* Bsrc = Bg + (long long)(n0 + w * 8 + sr) * ldb + ss * 8;

    f32x4 acc[8][4] = {};

    // half h covers rows h*128..h*128+127 -> 2 instrs (i = 0,1), 64 rows each.
    auto stageA = [&](int p, int kt, int h) {
#pragma unroll
        for (int i = 0; i < 2; ++i)
            __builtin_amdgcn_global_load_lds(
                (const __attribute__((address_space(1))) void*)(Asrc + (long long)(h * 128 + i * 64) * lda + kt),
                (__attribute__((address_space(3))) void*)(lds + p * 32768 + (h * 128 + i * 64 + w * 8) * 128), 16, 0, 0);
    };
    auto stageB = [&](int p, int kt, int h) {
#pragma unroll
        for (int i = 0; i < 2; ++i)
            __builtin_amdgcn_global_load_lds(
                (const __attribute__((address_space(1))) void*)(Bsrc + (long long)(h * 128 + i * 64) * ldb + kt),
                (__attribute__((address_space(3))) void*)(lds + 65536 + p * 32768 + (h * 128 + i * 64 + w * 8) * 128), 16, 0, 0);
    };

    // read addressing: row r holds logical 16B slot q at LDS slot q ^ (r&7).
    const unsigned ldsb = lds_off(lds);
    const unsigned as0  = (unsigned)(((l4    ) ^ (l15 & 7)) * 16);
    const unsigned as1  = (unsigned)(((l4 + 4) ^ (l15 & 7)) * 16);
    const unsigned aRow = (unsigned)((wm * 128 + l15) * 128);
    const unsigned bRow = (unsigned)((wn * 64 + l15) * 128);

    bf16x8 aA[4], aB[4], aC[4], aD[4], bA[4], bB[4];
    auto readA = [&](bf16x8 (&af)[4], int p, int mh, int ks) {
        unsigned base = ldsb + (unsigned)(p * 32768) + aRow + (unsigned)(mh * 8192) + (ks ? as1 : as0);
#pragma unroll
        for (int fi = 0; fi < 4; ++fi) {
            unsigned off = base + (unsigned)(fi * 2048);
            asm volatile("ds_read_b128 %0, %1" : "=v"(af[fi]) : "v"(off));
        }
    };
    auto readB = [&](bf16x8 (&bf)[4], int p, int ks) {
        unsigned base = ldsb + 65536u + (unsigned)(p * 32768) + bRow + (ks ? as1 : as0);
#pragma unroll
        for (int nj = 0; nj < 4; ++nj) {
            unsigned off = base + (unsigned)(nj * 2048);
            asm volatile("ds_read_b128 %0, %1" : "=v"(bf[nj]) : "v"(off));
        }
    };
    auto mfma16 = [&](int mh, bf16x8 (&af)[4], bf16x8 (&bf)[4]) {
#pragma unroll
        for (int fi = 0; fi < 4; ++fi)
#pragma unroll
            for (int nj = 0; nj < 4; ++nj)
                acc[mh * 4 + fi][nj] = __builtin_amdgcn_mfma_f32_16x16x32_bf16(
                    af[fi], bf[nj], acc[mh * 4 + fi][nj], 0, 0, 0);
    };

#define VMCNT0 asm volatile("s_waitcnt vmcnt(0)" ::: "memory")
#define LGKM8  asm volatile("s_waitcnt lgkmcnt(8)" ::: "memory")
#define LGKM4  asm volatile("s_waitcnt lgkmcnt(4)" ::: "memory")
#define LGKM0  asm volatile("s_waitcnt lgkmcnt(0)" ::: "memory")
#define SCHED0 __builtin_amdgcn_sched_barrier(0)
#define BARR   __builtin_amdgcn_s_barrier()
#define PRIO1  __builtin_amdgcn_s_setprio(1)
#define PRIO0  __builtin_amdgcn_s_setprio(0)

    const int NT = K >> 6;
    // prologue: stage tile 0 into buf 0
    stageA(0, 0, 0); stageA(0, 0, 1); stageB(0, 0, 0); stageB(0, 0, 1);

    for (int t = 0; t < NT; ++t) {
        const int p = t & 1, q = p ^ 1;
        // gate: buf p fully staged (loads issued last tile, full-tile lead -> no real
        // wait); barrier = WAR fence so staging q below is safe for all waves.
        VMCNT0; BARR; SCHED0;
        if (t + 1 < NT) {
            const int kt1 = (t + 1) << 6;
            stageA(q, kt1, 0); stageA(q, kt1, 1);
            stageB(q, kt1, 0); stageB(q, kt1, 1);
        }
        SCHED0;
        // phase 0 frags (8 reads) + phase 1 frags (4 reads) issued up front
        readA(aA, p, 0, 0); readB(bA, p, 0);
        readA(aB, p, 1, 0);
        LGKM4; SCHED0; PRIO1; mfma16(0, aA, bA); PRIO0;   // phase 0 (p1 reads stream under it)
        readA(aC, p, 0, 1); readB(bB, p, 1);              // phase 2 frags (8 reads)
        LGKM8; SCHED0; PRIO1; mfma16(1, aB, bA); PRIO0;   // phase 1
        readA(aD, p, 1, 1);                               // phase 3 frags (4 reads)
        LGKM4; SCHED0; PRIO1; mfma16(0, aC, bB); PRIO0;   // phase 2
        LGKM0; SCHED0; PRIO1; mfma16(1, aD, bB); PRIO0;   // phase 3
    }

    // epilogue: C/D frag layout col = lane&15 (N), row = (lane>>4)*4 + r (M)
    const float* bias_v = bias;
    asm volatile("" : "+s"(bias_v));   // keep bias loads out of the counted region
    unsigned short* Cb = (unsigned short*)Cv;
    float* Cf = (float*)Cv;
    long long cbase = (long long)bz * strideC;
#pragma unroll
    for (int mh = 0; mh < 2; ++mh)
#pragma unroll
    for (int fi = 0; fi < 4; ++fi) {
#pragma unroll
        for (int nj = 0; nj < 4; ++nj) {
            int n = n0 + wn * 64 + nj * 16 + l15;
            float bn = (BIAS_MODE == 1) ? bias_v[n] : 0.0f;
#pragma unroll
            for (int r = 0; r < 4; ++r) {
                int m = m0 + wm * 128 + mh * 64 + fi * 16 + l4 * 4 + r;
                float v = acc[mh * 4 + fi][nj][r] * scale + bn;
                if (BIAS_MODE == 2) v += bias_v[m];
                long long idx = cbase + (long long)m * ldc + n;
                if (OUT_MODE == 0) Cb[idx] = f2bf(v);
                else               Cf[idx] = v;
            }
        }
    }
}

// ------- row softmax over bf16 scores, in place: S[row][2048] bf16 -> P bf16 -------
__global__ __launch_bounds__(256) void softmax_rows_bf16(unsigned short* __restrict__ S) {
    int row  = blockIdx.x * 4 + (threadIdx.x >> 6);
    int lane = threadIdx.x & 63;
    unsigned short* Srow = S + (long long)row * 2048;
    float v[32];
    float mx = -1e30f;
#pragma unroll
    for (int j = 0; j < 4; ++j) {
        bf16x8 h = *(const bf16x8*)(Srow + j * 512 + lane * 8);
#pragma unroll
        for (int e = 0; e < 8; ++e) {
            float f = bf2f((unsigned short)h[e]);
            v[j * 8 + e] = f;
            mx = fmaxf(mx, f);
        }
    }
#pragma unroll
    for (int o = 32; o; o >>= 1) mx = fmaxf(mx, __shfl_xor(mx, o));
    float sum = 0.0f;
#pragma unroll
    for (int e = 0; e < 32; ++e) {
        v[e] = __expf(v[e] - mx);
        sum += v[e];
    }
#pragma unroll
    for (int o = 32; o; o >>= 1) sum += __shfl_xor(sum, o);
    float inv = 1.0f / sum;
#pragma unroll
    for (int j = 0; j < 4; ++j) {
        bf16x8 h;
#pragma unroll
        for (int e = 0; e < 8; ++e) h[e] = (short)f2bf(v[j * 8 + e] * inv);
        *(bf16x8*)(Srow + j * 512 + lane * 8) = h;
    }
}

extern "C" void kernel_launch(void* const* d_in, const int* in_sizes, int n_in,
                              void* d_out, int out_size, void* d_ws, size_t ws_size,
                              hipStream_t stream) {
    (void)in_sizes; (void)n_in; (void)out_size; (void)ws_size;
    const float* x  = (const float*)d_in[0];
    const float* Wq = (const float*)d_in[1];
    const float* bq = (const float*)d_in[2];
    const float* Wk = (const float*)d_in[3];
    const float* bk = (const float*)d_in[4];
    const float* Wv = (const float*)d_in[5];
    const float* bv = (const float*)d_in[6];

    // workspace layout (bytes) — peak ~166 MiB
    char* ws = (char*)d_ws;
    unsigned short* Wt  = (unsigned short*)ws;                       //   6,291,456 B (q,k,v)
    unsigned short* Qb  = (unsigned short*)(ws + 6291456);           //  33,554,432
    unsigned short* Kb  = (unsigned short*)(ws + 39845888);          //  33,554,432
    unsigned short* Vt  = (unsigned short*)(ws + 73400320);          //  33,554,432
    unsigned short* xb  = (unsigned short*)(ws + 106954752);         //  33,554,432 (dead after V proj)
    unsigned short* Sb  = (unsigned short*)(ws + 106954752);         //  67,108,864 (bf16 scores, overlays xb)

    // 1) convert x -> bf16
    cvt_f32_bf16<<<dim3(16384), dim3(256), 0, stream>>>(x, xb);
    // 2) W^T -> bf16 (3 mats)
    transpose_w<<<dim3(32, 32, 3), dim3(32, 8), 0, stream>>>(Wq, Wk, Wv, Wt);

    // 3) Q = xb @ Wq + bq   -> bf16 [16384][1024]
    gemmpp<0, 1><<<dim3(4, 64, 1), dim3(512), 0, stream>>>(
        xb, 1024, 0, Wt, 1024, 0, Qb, 1024, 0, bq, 1024, 1.0f);
    // 4) K
    gemmpp<0, 1><<<dim3(4, 64, 1), dim3(512), 0, stream>>>(
        xb, 1024, 0, Wt + 1048576, 1024, 0, Kb, 1024, 0, bk, 1024, 1.0f);
    // 5) Vt[d][m] = sum_k Wvt[d][k] xb[m][k] + bv[d]  -> bf16 [1024][16384]
    gemmpp<0, 2><<<dim3(64, 4, 1), dim3(512), 0, stream>>>(
        Wt + 2097152, 1024, 0, xb, 1024, 0, Vt, 16384, 0, bv, 1024, 1.0f);

    // 6) scores: S[b][q][kv] = (Q @ K^T) * 1/32   -> bf16 (xb dead now)
    gemmpp<0, 0><<<dim3(8, 8, 8), dim3(512), 0, stream>>>(
        Qb, 1024, 2097152LL, Kb, 1024, 2097152LL,
        Sb, 2048, 4194304LL, nullptr, 1024, 0.03125f);

    // 7) softmax rows in place (bf16 -> bf16)
    softmax_rows_bf16<<<dim3(4096), dim3(256), 0, stream>>>(Sb);

    // 8) out[b][q][d] = P @ V = sum_kv P[q][kv] * Vt[d][b*2048+kv]
    gemmpp<1, 0><<<dim3(4, 8, 8), dim3(512), 0, stream>>>(
        Sb, 2048, 4194304LL,
        Vt, 16384, 2048LL,
        d_out, 1024, 2097152LL, nullptr, 2048, 1.0f);
}